// Round 6
// baseline (327.731 us; speedup 1.0000x reference)
//
#include <hip/hip_runtime.h>
#include <hip/hip_bf16.h>

// 2-layer GCN on MI355X.
// out[v] = dinv[v] * ( sum_{e: dst=v} g[src_e] + g[v] ) + b,  g = (x@W) * dinv[row]
// dinv[v] = rsqrt(indeg(v) + 1)
// CSR build = bucketed counting sort, ALL atomics in LDS (no device atomics).
// g1/g2 stored BF16; aggregate uses 16-deep gather pipelining (avg degree = 16).

#define FDIM 64    // HID_DIM == OUT_DIM
#define NPB  128   // nodes per bucket (dst >> 7)
#define MAXB1 800  // >= ceil(100000/128)=782

// bf16 helpers (bit-level, RTN; finite data only)
static __device__ __forceinline__ unsigned short f2bf(float f) {
    unsigned int u = __float_as_uint(f);
    unsigned int r = 0x7FFFu + ((u >> 16) & 1u);
    return (unsigned short)((u + r) >> 16);
}
static __device__ __forceinline__ float bf2f(unsigned short u) {
    return __uint_as_float((unsigned int)u << 16);
}

// ---------------- phase 1a: per-block bucket histogram ----------------
__global__ __launch_bounds__(256) void bucket_hist(const int* __restrict__ dst, int E,
                                                   int B1, int chunk, int B0,
                                                   int* __restrict__ H) {
    __shared__ int hist[MAXB1];
    const int blk = blockIdx.x, t = threadIdx.x;
    for (int i = t; i < B1; i += 256) hist[i] = 0;
    __syncthreads();
    const int beg = blk * chunk, end = min(E, beg + chunk);
    for (int e = beg + t; e < end; e += 256) atomicAdd(&hist[dst[e] >> 7], 1);
    __syncthreads();
    for (int i = t; i < B1; i += 256) H[i * B0 + blk] = hist[i];  // bin-major
}

// ---------------- scan A: per-block sums over spans of 2048 ----------------
__global__ __launch_bounds__(256) void scanA(const int* __restrict__ a, int S,
                                             int* __restrict__ bs) {
    __shared__ int s[256];
    const int blk = blockIdx.x, t = threadIdx.x;
    const int base = blk * 2048 + t * 8;
    int sum = 0;
    #pragma unroll
    for (int j = 0; j < 8; ++j) { int idx = base + j; if (idx < S) sum += a[idx]; }
    s[t] = sum;
    __syncthreads();
    for (int off = 128; off > 0; off >>= 1) {
        if (t < off) s[t] += s[t + off];
        __syncthreads();
    }
    if (t == 0) bs[blk] = s[0];
}

// ---------------- scan B: exclusive scan of block sums (nB <= 512) ----------
__global__ __launch_bounds__(512) void scanB(int* __restrict__ bs, int nB) {
    __shared__ int s[512];
    const int t = threadIdx.x;
    int v = (t < nB) ? bs[t] : 0;
    s[t] = v;
    __syncthreads();
    for (int off = 1; off < 512; off <<= 1) {
        int x = s[t];
        int y = (t >= off) ? s[t - off] : 0;
        __syncthreads();
        s[t] = x + y;
        __syncthreads();
    }
    if (t < nB) bs[t] = s[t] - v;
}

// ---------------- scan C: in-place exclusive scan (span 2048/block) ---------
__global__ __launch_bounds__(256) void scanC(int* __restrict__ a, int S,
                                             const int* __restrict__ bs) {
    __shared__ int s[256];
    const int blk = blockIdx.x, t = threadIdx.x;
    const int base = blk * 2048 + t * 8;
    int v[8];
    int sum = 0;
    #pragma unroll
    for (int j = 0; j < 8; ++j) { int idx = base + j; v[j] = (idx < S) ? a[idx] : 0; sum += v[j]; }
    s[t] = sum;
    __syncthreads();
    const int own = sum;
    for (int off = 1; off < 256; off <<= 1) {
        int x = s[t];
        int y = (t >= off) ? s[t - off] : 0;
        __syncthreads();
        s[t] = x + y;
        __syncthreads();
    }
    int run = bs[blk] + s[t] - own;   // exclusive prefix for this thread's segment
    #pragma unroll
    for (int j = 0; j < 8; ++j) { int idx = base + j; if (idx < S) a[idx] = run; run += v[j]; }
}

// ------- phase 1b: scatter edges into bucket-grouped packed (dlow7,src) -----
__global__ __launch_bounds__(256) void bucket_scatter(const int* __restrict__ src,
                                                      const int* __restrict__ dst,
                                                      int E, int B1, int chunk, int B0,
                                                      const int* __restrict__ Hs,
                                                      int* __restrict__ pairs) {
    __shared__ int cur[MAXB1];
    const int blk = blockIdx.x, t = threadIdx.x;
    for (int i = t; i < B1; i += 256) cur[i] = Hs[i * B0 + blk];
    __syncthreads();
    const int beg = blk * chunk, end = min(E, beg + chunk);
    for (int e = beg + t; e < end; e += 256) {
        int d = dst[e];
        int pos = atomicAdd(&cur[d >> 7], 1);          // LDS atomic
        pairs[pos] = ((d & 127) << 17) | src[e];       // src < 2^17
    }
}

// ---------------- phase 2: per-bucket local counting sort -> CSR ------------
__global__ __launch_bounds__(256) void bucket_csr(const int* __restrict__ pairs,
                                                  const int* __restrict__ Hs,
                                                  int B0, int E, int N,
                                                  float* __restrict__ dinv,
                                                  int* __restrict__ rowStart,
                                                  int* __restrict__ srcSorted) {
    __shared__ int hist[NPB], pref[NPB], cur[NPB];
    const int b = blockIdx.x, t = threadIdx.x;
    const int B1 = gridDim.x;
    const int vbase = b * NPB;
    const int nv = min(NPB, N - vbase);
    const int estart = Hs[b * B0];
    const int eend = (b + 1 < B1) ? Hs[(b + 1) * B0] : E;

    if (t < NPB) hist[t] = 0;
    __syncthreads();
    for (int e = estart + t; e < eend; e += 256)
        atomicAdd(&hist[pairs[e] >> 17], 1);
    __syncthreads();

    if (t < NPB) pref[t] = hist[t];
    __syncthreads();
    for (int off = 1; off < NPB; off <<= 1) {
        int v = 0;
        if (t < NPB && t >= off) v = pref[t - off];
        __syncthreads();
        if (t < NPB) pref[t] += v;
        __syncthreads();
    }
    if (t < nv) {
        int ex = pref[t] - hist[t];          // exclusive prefix
        rowStart[vbase + t] = estart + ex;
        dinv[vbase + t] = rsqrtf((float)(hist[t] + 1));
        cur[t] = estart + ex;
    }
    if (b == B1 - 1 && t == 0) rowStart[N] = E;
    __syncthreads();
    for (int e = estart + t; e < eend; e += 256) {
        int p = pairs[e];
        int pos = atomicAdd(&cur[p >> 17], 1);       // LDS atomic
        srcSorted[pos] = p & 0x1FFFF;
    }
}

// ---------------- GEMM: W in LDS, 16 outputs/thread, bf16 output ------------
template <int K>
__global__ __launch_bounds__(256) void gemm_scale(const float* __restrict__ X,
                                                  const float* __restrict__ W,
                                                  const float* __restrict__ dinv,
                                                  unsigned short* __restrict__ G, int N) {
    __shared__ float Wl[K * FDIM];
    const int t = threadIdx.x;
    {
        const float4* Wv  = reinterpret_cast<const float4*>(W);
        float4*       Wlv = reinterpret_cast<float4*>(Wl);
        #pragma unroll
        for (int i = 0; i < (K * FDIM) / (256 * 4); ++i)
            Wlv[i * 256 + t] = Wv[i * 256 + t];
    }
    __syncthreads();

    const int r   = t >> 2;
    const int q   = t & 3;
    const int row = blockIdx.x * 64 + r;
    if (row >= N) return;

    const float4* xr  = reinterpret_cast<const float4*>(X + (size_t)row * K);
    const float4* wlq = reinterpret_cast<const float4*>(Wl) + q * 4;

    float acc[16];
    #pragma unroll
    for (int i = 0; i < 16; ++i) acc[i] = 0.f;

    #pragma unroll 2
    for (int k4 = 0; k4 < K / 4; ++k4) {
        float4 xv = xr[k4];
        float xs[4] = {xv.x, xv.y, xv.z, xv.w};
        #pragma unroll
        for (int j = 0; j < 4; ++j) {
            const float4* wrow = wlq + (size_t)(4 * k4 + j) * 16;
            float4 w0 = wrow[0], w1 = wrow[1], w2 = wrow[2], w3 = wrow[3];
            float xk = xs[j];
            acc[ 0] += xk * w0.x; acc[ 1] += xk * w0.y; acc[ 2] += xk * w0.z; acc[ 3] += xk * w0.w;
            acc[ 4] += xk * w1.x; acc[ 5] += xk * w1.y; acc[ 6] += xk * w1.z; acc[ 7] += xk * w1.w;
            acc[ 8] += xk * w2.x; acc[ 9] += xk * w2.y; acc[10] += xk * w2.z; acc[11] += xk * w2.w;
            acc[12] += xk * w3.x; acc[13] += xk * w3.y; acc[14] += xk * w3.z; acc[15] += xk * w3.w;
        }
    }

    const float dv = dinv[row];
    unsigned int p[8];
    #pragma unroll
    for (int i = 0; i < 8; ++i) {
        unsigned int lo = f2bf(acc[2 * i] * dv);
        unsigned int hi = f2bf(acc[2 * i + 1] * dv);
        p[i] = lo | (hi << 16);
    }
    uint4* gout = reinterpret_cast<uint4*>(G + (size_t)row * FDIM + q * 16);
    gout[0] = make_uint4(p[0], p[1], p[2], p[3]);
    gout[1] = make_uint4(p[4], p[5], p[6], p[7]);
}

// ------- aggregate: wave/node, 16-deep gather pipeline, jagged tail ---------
__global__ __launch_bounds__(256) void aggregate(const unsigned short* __restrict__ G,
                                                 const int* __restrict__ rowStart,
                                                 const int* __restrict__ srcSorted,
                                                 const float* __restrict__ dinv,
                                                 const float* __restrict__ bias,
                                                 float* __restrict__ OUT, int N, int doRelu) {
    const int lane   = threadIdx.x & 63;
    const int waveId = blockIdx.x * (blockDim.x >> 6) + (threadIdx.x >> 6);
    const int nWaves = gridDim.x * (blockDim.x >> 6);
    const float b = bias[lane];

    for (int v = waveId; v < N; v += nWaves) {
        const int beg = rowStart[v];
        const int end = rowStart[v + 1];
        float acc = bf2f(G[(size_t)v * FDIM + lane]);   // self loop
        int e = beg;

        // full 16-edge blocks: 16 index loads -> 16 independent gathers -> adds
        for (; e + 16 <= end; e += 16) {
            int idx[16];
            #pragma unroll
            for (int j = 0; j < 16; ++j) idx[j] = srcSorted[e + j];
            unsigned short gv[16];
            #pragma unroll
            for (int j = 0; j < 16; ++j) gv[j] = G[(size_t)idx[j] * FDIM + lane];
            float s = 0.f;
            #pragma unroll
            for (int j = 0; j < 16; ++j) s += bf2f(gv[j]);
            acc += s;
        }

        // jagged tail (t in 1..15): ONE load round + ONE gather round,
        // wave-uniform scalar branches (t uniform per wave -> no divergence)
        const int t = end - e;
        if (t > 0) {
            int idx[15];
            #pragma unroll
            for (int j = 0; j < 15; ++j) idx[j] = srcSorted[e + min(j, t - 1)];
            unsigned short gv[15];
            #pragma unroll
            for (int j = 0; j < 15; ++j) { if (j < t) gv[j] = G[(size_t)idx[j] * FDIM + lane]; }
            #pragma unroll
            for (int j = 0; j < 15; ++j) { if (j < t) acc += bf2f(gv[j]); }
        }

        float r = acc * dinv[v] + b;
        if (doRelu) r = fmaxf(r, 0.f);
        OUT[(size_t)v * FDIM + lane] = r;
    }
}

extern "C" void kernel_launch(void* const* d_in, const int* in_sizes, int n_in,
                              void* d_out, int out_size, void* d_ws, size_t ws_size,
                              hipStream_t stream) {
    const float* x     = (const float*)d_in[0];
    const int*   edges = (const int*)d_in[1];   // int32 per harness contract
    const float* W1    = (const float*)d_in[2];
    const float* b1    = (const float*)d_in[3];
    const float* W2    = (const float*)d_in[4];
    const float* b2    = (const float*)d_in[5];
    float*       out   = (float*)d_out;

    const int N = in_sizes[0] / 128;   // 100000
    const int E = in_sizes[1] / 2;     // 1600000
    const int* srcIdx = edges;
    const int* dstIdx = edges + E;

    const int B1 = (N + NPB - 1) / NPB;         // 782 buckets
    const int B0 = 256;                          // phase-1 blocks
    const int chunk = (E + B0 - 1) / B0;         // 6250
    const int S  = B1 * B0;                      // scanned size (200192)
    const int nSB = (S + 2047) / 2048;           // 98 scan blocks (<=512)

    // workspace layout (256B aligned slices)
    char* ws = (char*)d_ws;
    size_t off = 0;
    auto alloc = [&](size_t bytes) { char* p = ws + off; off = (off + bytes + 255) & ~(size_t)255; return p; };
    float* dinv      = (float*)alloc((size_t)N * 4);
    int*   H         = (int*)  alloc((size_t)S * 4);
    int*   blockSums = (int*)  alloc(512 * 4);
    int*   rowStart  = (int*)  alloc((size_t)(N + 1) * 4);
    int*   srcSorted = (int*)  alloc((size_t)E * 4);
    unsigned short* g1 = (unsigned short*)alloc((size_t)N * FDIM * 2);  // bf16
    float* x2        = (float*)alloc((size_t)N * FDIM * 4);
    int*   pairs     = (int*)x2;        // alias: pairs dead before x2 written
    unsigned short* g2 = g1;            // g1 dead after first aggregate

    const int gT = (N + 63) / 64;   // GEMM tiles

    bucket_hist   <<<B0, 256, 0, stream>>>(dstIdx, E, B1, chunk, B0, H);
    scanA         <<<nSB, 256, 0, stream>>>(H, S, blockSums);
    scanB         <<<1, 512, 0, stream>>>(blockSums, nSB);
    scanC         <<<nSB, 256, 0, stream>>>(H, S, blockSums);
    bucket_scatter<<<B0, 256, 0, stream>>>(srcIdx, dstIdx, E, B1, chunk, B0, H, pairs);
    bucket_csr    <<<B1, 256, 0, stream>>>(pairs, H, B0, E, N, dinv, rowStart, srcSorted);

    gemm_scale<128><<<gT, 256, 0, stream>>>(x,  W1, dinv, g1, N);
    aggregate      <<<2048, 256, 0, stream>>>(g1, rowStart, srcSorted, dinv, b1, x2, N, 1);
    gemm_scale<64> <<<gT, 256, 0, stream>>>(x2, W2, dinv, g2, N);
    aggregate      <<<2048, 256, 0, stream>>>(g2, rowStart, srcSorted, dinv, b2, out, N, 0);
}

// Round 7
// 200.393 us; speedup vs baseline: 1.6354x; 1.6354x over previous
//
#include <hip/hip_runtime.h>
#include <hip/hip_bf16.h>

// 2-layer GCN on MI355X.
// out[v] = dinv[v] * ( sum_{e: dst=v} g[src_e] + g[v] ) + b,  g = (x@W) * dinv[row]
// dinv[v] = rsqrt(indeg(v) + 1)
// CSR build = bucketed counting sort, ALL atomics in LDS (no device atomics).
// g1/g2 stored BF16. aggregate: half-wave pair-gather (1 uint = 2 features,
// lanes 0-31 even edge / 32-63 odd edge), named-scalar 8-deep pipeline
// (NO arrays -> no scratch; r6 lesson: arrays spilled, VGPR 36, occ 43%).

#define FDIM 64    // HID_DIM == OUT_DIM
#define NPB  128   // nodes per bucket (dst >> 7)
#define MAXB1 800  // >= ceil(100000/128)=782

// bf16 helpers (bit-level; finite data only)
static __device__ __forceinline__ unsigned short f2bf(float f) {
    unsigned int u = __float_as_uint(f);
    unsigned int r = 0x7FFFu + ((u >> 16) & 1u);
    return (unsigned short)((u + r) >> 16);
}
static __device__ __forceinline__ float lof(unsigned int u) {   // low bf16 -> f32
    return __uint_as_float(u << 16);
}
static __device__ __forceinline__ float hif(unsigned int u) {   // high bf16 -> f32
    return __uint_as_float(u & 0xFFFF0000u);
}

// ---------------- phase 1a: per-block bucket histogram ----------------
__global__ __launch_bounds__(256) void bucket_hist(const int* __restrict__ dst, int E,
                                                   int B1, int chunk, int B0,
                                                   int* __restrict__ H) {
    __shared__ int hist[MAXB1];
    const int blk = blockIdx.x, t = threadIdx.x;
    for (int i = t; i < B1; i += 256) hist[i] = 0;
    __syncthreads();
    const int beg = blk * chunk, end = min(E, beg + chunk);
    for (int e = beg + t; e < end; e += 256) atomicAdd(&hist[dst[e] >> 7], 1);
    __syncthreads();
    for (int i = t; i < B1; i += 256) H[i * B0 + blk] = hist[i];  // bin-major
}

// ---------------- scan A: per-block sums over spans of 2048 ----------------
__global__ __launch_bounds__(256) void scanA(const int* __restrict__ a, int S,
                                             int* __restrict__ bs) {
    __shared__ int s[256];
    const int blk = blockIdx.x, t = threadIdx.x;
    const int base = blk * 2048 + t * 8;
    int sum = 0;
    #pragma unroll
    for (int j = 0; j < 8; ++j) { int idx = base + j; if (idx < S) sum += a[idx]; }
    s[t] = sum;
    __syncthreads();
    for (int off = 128; off > 0; off >>= 1) {
        if (t < off) s[t] += s[t + off];
        __syncthreads();
    }
    if (t == 0) bs[blk] = s[0];
}

// ---------------- scan B: exclusive scan of block sums (nB <= 512) ----------
__global__ __launch_bounds__(512) void scanB(int* __restrict__ bs, int nB) {
    __shared__ int s[512];
    const int t = threadIdx.x;
    int v = (t < nB) ? bs[t] : 0;
    s[t] = v;
    __syncthreads();
    for (int off = 1; off < 512; off <<= 1) {
        int x = s[t];
        int y = (t >= off) ? s[t - off] : 0;
        __syncthreads();
        s[t] = x + y;
        __syncthreads();
    }
    if (t < nB) bs[t] = s[t] - v;
}

// ---------------- scan C: in-place exclusive scan (span 2048/block) ---------
__global__ __launch_bounds__(256) void scanC(int* __restrict__ a, int S,
                                             const int* __restrict__ bs) {
    __shared__ int s[256];
    const int blk = blockIdx.x, t = threadIdx.x;
    const int base = blk * 2048 + t * 8;
    int v[8];
    int sum = 0;
    #pragma unroll
    for (int j = 0; j < 8; ++j) { int idx = base + j; v[j] = (idx < S) ? a[idx] : 0; sum += v[j]; }
    s[t] = sum;
    __syncthreads();
    const int own = sum;
    for (int off = 1; off < 256; off <<= 1) {
        int x = s[t];
        int y = (t >= off) ? s[t - off] : 0;
        __syncthreads();
        s[t] = x + y;
        __syncthreads();
    }
    int run = bs[blk] + s[t] - own;   // exclusive prefix for this thread's segment
    #pragma unroll
    for (int j = 0; j < 8; ++j) { int idx = base + j; if (idx < S) a[idx] = run; run += v[j]; }
}

// ------- phase 1b: scatter edges into bucket-grouped packed (dlow7,src) -----
__global__ __launch_bounds__(256) void bucket_scatter(const int* __restrict__ src,
                                                      const int* __restrict__ dst,
                                                      int E, int B1, int chunk, int B0,
                                                      const int* __restrict__ Hs,
                                                      int* __restrict__ pairs) {
    __shared__ int cur[MAXB1];
    const int blk = blockIdx.x, t = threadIdx.x;
    for (int i = t; i < B1; i += 256) cur[i] = Hs[i * B0 + blk];
    __syncthreads();
    const int beg = blk * chunk, end = min(E, beg + chunk);
    for (int e = beg + t; e < end; e += 256) {
        int d = dst[e];
        int pos = atomicAdd(&cur[d >> 7], 1);          // LDS atomic
        pairs[pos] = ((d & 127) << 17) | src[e];       // src < 2^17
    }
}

// ---------------- phase 2: per-bucket local counting sort -> CSR ------------
__global__ __launch_bounds__(256) void bucket_csr(const int* __restrict__ pairs,
                                                  const int* __restrict__ Hs,
                                                  int B0, int E, int N,
                                                  float* __restrict__ dinv,
                                                  int* __restrict__ rowStart,
                                                  int* __restrict__ srcSorted) {
    __shared__ int hist[NPB], pref[NPB], cur[NPB];
    const int b = blockIdx.x, t = threadIdx.x;
    const int B1 = gridDim.x;
    const int vbase = b * NPB;
    const int nv = min(NPB, N - vbase);
    const int estart = Hs[b * B0];
    const int eend = (b + 1 < B1) ? Hs[(b + 1) * B0] : E;

    if (t < NPB) hist[t] = 0;
    __syncthreads();
    for (int e = estart + t; e < eend; e += 256)
        atomicAdd(&hist[pairs[e] >> 17], 1);
    __syncthreads();

    if (t < NPB) pref[t] = hist[t];
    __syncthreads();
    for (int off = 1; off < NPB; off <<= 1) {
        int v = 0;
        if (t < NPB && t >= off) v = pref[t - off];
        __syncthreads();
        if (t < NPB) pref[t] += v;
        __syncthreads();
    }
    if (t < nv) {
        int ex = pref[t] - hist[t];          // exclusive prefix
        rowStart[vbase + t] = estart + ex;
        dinv[vbase + t] = rsqrtf((float)(hist[t] + 1));
        cur[t] = estart + ex;
    }
    if (b == B1 - 1 && t == 0) rowStart[N] = E;
    __syncthreads();
    for (int e = estart + t; e < eend; e += 256) {
        int p = pairs[e];
        int pos = atomicAdd(&cur[p >> 17], 1);       // LDS atomic
        srcSorted[pos] = p & 0x1FFFF;
    }
}

// ---------------- GEMM: W in LDS, 16 outputs/thread, bf16 output ------------
template <int K>
__global__ __launch_bounds__(256) void gemm_scale(const float* __restrict__ X,
                                                  const float* __restrict__ W,
                                                  const float* __restrict__ dinv,
                                                  unsigned short* __restrict__ G, int N) {
    __shared__ float Wl[K * FDIM];
    const int t = threadIdx.x;
    {
        const float4* Wv  = reinterpret_cast<const float4*>(W);
        float4*       Wlv = reinterpret_cast<float4*>(Wl);
        #pragma unroll
        for (int i = 0; i < (K * FDIM) / (256 * 4); ++i)
            Wlv[i * 256 + t] = Wv[i * 256 + t];
    }
    __syncthreads();

    const int r   = t >> 2;
    const int q   = t & 3;
    const int row = blockIdx.x * 64 + r;
    if (row >= N) return;

    const float4* xr  = reinterpret_cast<const float4*>(X + (size_t)row * K);
    const float4* wlq = reinterpret_cast<const float4*>(Wl) + q * 4;

    float acc[16];
    #pragma unroll
    for (int i = 0; i < 16; ++i) acc[i] = 0.f;

    #pragma unroll 2
    for (int k4 = 0; k4 < K / 4; ++k4) {
        float4 xv = xr[k4];
        float xs[4] = {xv.x, xv.y, xv.z, xv.w};
        #pragma unroll
        for (int j = 0; j < 4; ++j) {
            const float4* wrow = wlq + (size_t)(4 * k4 + j) * 16;
            float4 w0 = wrow[0], w1 = wrow[1], w2 = wrow[2], w3 = wrow[3];
            float xk = xs[j];
            acc[ 0] += xk * w0.x; acc[ 1] += xk * w0.y; acc[ 2] += xk * w0.z; acc[ 3] += xk * w0.w;
            acc[ 4] += xk * w1.x; acc[ 5] += xk * w1.y; acc[ 6] += xk * w1.z; acc[ 7] += xk * w1.w;
            acc[ 8] += xk * w2.x; acc[ 9] += xk * w2.y; acc[10] += xk * w2.z; acc[11] += xk * w2.w;
            acc[12] += xk * w3.x; acc[13] += xk * w3.y; acc[14] += xk * w3.z; acc[15] += xk * w3.w;
        }
    }

    const float dv = dinv[row];
    unsigned int p[8];
    #pragma unroll
    for (int i = 0; i < 8; ++i) {
        unsigned int lo = f2bf(acc[2 * i] * dv);
        unsigned int hi = f2bf(acc[2 * i + 1] * dv);
        p[i] = lo | (hi << 16);
    }
    uint4* gout = reinterpret_cast<uint4*>(G + (size_t)row * FDIM + q * 16);
    gout[0] = make_uint4(p[0], p[1], p[2], p[3]);
    gout[1] = make_uint4(p[4], p[5], p[6], p[7]);
}

// ------- aggregate: wave/node, half-wave pair-gather, named-scalar pipeline --
// Lanes 0-31 handle even edges, 32-63 odd edges; each lane gathers one uint
// (= 2 bf16 features) of the 32-uint row. Fold halves via shfl_xor(32).
#define GATHER2(ii, uu, off)  int ii = srcSorted[eb + 2*(off)]; \
                              unsigned int uu = Gu[(size_t)ii * 32 + fl];

__global__ __launch_bounds__(256, 4) void aggregate(const unsigned int* __restrict__ Gu,
                                                    const int* __restrict__ rowStart,
                                                    const int* __restrict__ srcSorted,
                                                    const float* __restrict__ dinv,
                                                    const float* __restrict__ bias,
                                                    float* __restrict__ OUT, int N, int doRelu) {
    const int lane   = threadIdx.x & 63;
    const int half   = lane >> 5;        // 0: even edges, 1: odd edges
    const int fl     = lane & 31;        // uint index within row (features 2fl,2fl+1)
    const int waveId = blockIdx.x * (blockDim.x >> 6) + (threadIdx.x >> 6);
    const int nWaves = gridDim.x * (blockDim.x >> 6);
    const float2 bv  = reinterpret_cast<const float2*>(bias)[fl];

    for (int v = waveId; v < N; v += nWaves) {
        const int beg = rowStart[v];
        const int end = rowStart[v + 1];

        // self-loop: only half 0 contributes (avoid double count after fold)
        unsigned int su = 0;
        if (half == 0) su = Gu[(size_t)v * 32 + fl];
        float ax = lof(su), ay = hif(su);

        int e = beg;
        // main: 16 edges (8 pairs) per round, named scalars only
        for (; e + 16 <= end; e += 16) {
            const int eb = e + half;
            GATHER2(i0, u0, 0) GATHER2(i1, u1, 1) GATHER2(i2, u2, 2) GATHER2(i3, u3, 3)
            GATHER2(i4, u4, 4) GATHER2(i5, u5, 5) GATHER2(i6, u6, 6) GATHER2(i7, u7, 7)
            ax += ((lof(u0) + lof(u1)) + (lof(u2) + lof(u3)))
                + ((lof(u4) + lof(u5)) + (lof(u6) + lof(u7)));
            ay += ((hif(u0) + hif(u1)) + (hif(u2) + hif(u3)))
                + ((hif(u4) + hif(u5)) + (hif(u6) + hif(u7)));
        }
        int rem = end - e;
        if (rem >= 8) {               // 4 pairs
            const int eb = e + half;
            GATHER2(i0, u0, 0) GATHER2(i1, u1, 1) GATHER2(i2, u2, 2) GATHER2(i3, u3, 3)
            ax += (lof(u0) + lof(u1)) + (lof(u2) + lof(u3));
            ay += (hif(u0) + hif(u1)) + (hif(u2) + hif(u3));
            e += 8; rem -= 8;
        }
        if (rem >= 4) {               // 2 pairs
            const int eb = e + half;
            GATHER2(i0, u0, 0) GATHER2(i1, u1, 1)
            ax += lof(u0) + lof(u1);
            ay += hif(u0) + hif(u1);
            e += 4; rem -= 4;
        }
        if (rem >= 2) {               // 1 pair
            const int eb = e + half;
            GATHER2(i0, u0, 0)
            ax += lof(u0);
            ay += hif(u0);
            e += 2; rem -= 2;
        }
        if (rem) {                    // single edge: half 0 only (exec-masked)
            int i0 = srcSorted[e];
            unsigned int u0 = 0;
            if (half == 0) u0 = Gu[(size_t)i0 * 32 + fl];
            ax += lof(u0);
            ay += hif(u0);
        }

        // fold halves
        ax += __shfl_xor(ax, 32, 64);
        ay += __shfl_xor(ay, 32, 64);

        const float dv = dinv[v];
        float2 r;
        r.x = ax * dv + bv.x;
        r.y = ay * dv + bv.y;
        if (doRelu) { r.x = fmaxf(r.x, 0.f); r.y = fmaxf(r.y, 0.f); }
        if (half == 0)
            reinterpret_cast<float2*>(OUT + (size_t)v * FDIM)[fl] = r;
    }
}

extern "C" void kernel_launch(void* const* d_in, const int* in_sizes, int n_in,
                              void* d_out, int out_size, void* d_ws, size_t ws_size,
                              hipStream_t stream) {
    const float* x     = (const float*)d_in[0];
    const int*   edges = (const int*)d_in[1];   // int32 per harness contract
    const float* W1    = (const float*)d_in[2];
    const float* b1    = (const float*)d_in[3];
    const float* W2    = (const float*)d_in[4];
    const float* b2    = (const float*)d_in[5];
    float*       out   = (float*)d_out;

    const int N = in_sizes[0] / 128;   // 100000
    const int E = in_sizes[1] / 2;     // 1600000
    const int* srcIdx = edges;
    const int* dstIdx = edges + E;

    const int B1 = (N + NPB - 1) / NPB;         // 782 buckets
    const int B0 = 256;                          // phase-1 blocks
    const int chunk = (E + B0 - 1) / B0;         // 6250
    const int S  = B1 * B0;                      // scanned size (200192)
    const int nSB = (S + 2047) / 2048;           // 98 scan blocks (<=512)

    // workspace layout (256B aligned slices)
    char* ws = (char*)d_ws;
    size_t off = 0;
    auto alloc = [&](size_t bytes) { char* p = ws + off; off = (off + bytes + 255) & ~(size_t)255; return p; };
    float* dinv      = (float*)alloc((size_t)N * 4);
    int*   H         = (int*)  alloc((size_t)S * 4);
    int*   blockSums = (int*)  alloc(512 * 4);
    int*   rowStart  = (int*)  alloc((size_t)(N + 1) * 4);
    int*   srcSorted = (int*)  alloc((size_t)E * 4);
    unsigned short* g1 = (unsigned short*)alloc((size_t)N * FDIM * 2);  // bf16
    float* x2        = (float*)alloc((size_t)N * FDIM * 4);
    int*   pairs     = (int*)x2;        // alias: pairs dead before x2 written
    unsigned short* g2 = g1;            // g1 dead after first aggregate

    const int gT = (N + 63) / 64;   // GEMM tiles

    bucket_hist   <<<B0, 256, 0, stream>>>(dstIdx, E, B1, chunk, B0, H);
    scanA         <<<nSB, 256, 0, stream>>>(H, S, blockSums);
    scanB         <<<1, 512, 0, stream>>>(blockSums, nSB);
    scanC         <<<nSB, 256, 0, stream>>>(H, S, blockSums);
    bucket_scatter<<<B0, 256, 0, stream>>>(srcIdx, dstIdx, E, B1, chunk, B0, H, pairs);
    bucket_csr    <<<B1, 256, 0, stream>>>(pairs, H, B0, E, N, dinv, rowStart, srcSorted);

    gemm_scale<128><<<gT, 256, 0, stream>>>(x,  W1, dinv, g1, N);
    aggregate      <<<2048, 256, 0, stream>>>((const unsigned int*)g1, rowStart, srcSorted, dinv, b1, x2, N, 1);
    gemm_scale<64> <<<gT, 256, 0, stream>>>(x2, W2, dinv, g2, N);
    aggregate      <<<2048, 256, 0, stream>>>((const unsigned int*)g2, rowStart, srcSorted, dinv, b2, out, N, 0);
}

// Round 8
// 191.988 us; speedup vs baseline: 1.7070x; 1.0438x over previous
//
#include <hip/hip_runtime.h>
#include <hip/hip_bf16.h>

// 2-layer GCN on MI355X.
// out[v] = dinv[v] * ( sum_{e: dst=v} g[src_e] + g[v] ) + b,  g = (x@W) * dinv[row]
// dinv[v] = rsqrt(indeg(v) + 1)
// CSR build = bucketed counting sort, ALL atomics in LDS (no device atomics).
// g1/g2 stored BF16. aggregate: half-wave pair-gather, named-scalar pipeline.
// GEMM: W in LDS, 4 rows x 8 cols per thread (1 B LDS per FMA; r7 was 4 B/FMA
// -> LDS-throughput-bound at 51 us).

#define FDIM 64    // HID_DIM == OUT_DIM
#define NPB  128   // nodes per bucket (dst >> 7)
#define MAXB1 800  // >= ceil(100000/128)=782

// bf16 helpers (bit-level; finite data only)
static __device__ __forceinline__ unsigned short f2bf(float f) {
    unsigned int u = __float_as_uint(f);
    unsigned int r = 0x7FFFu + ((u >> 16) & 1u);
    return (unsigned short)((u + r) >> 16);
}
static __device__ __forceinline__ float lof(unsigned int u) {   // low bf16 -> f32
    return __uint_as_float(u << 16);
}
static __device__ __forceinline__ float hif(unsigned int u) {   // high bf16 -> f32
    return __uint_as_float(u & 0xFFFF0000u);
}

// ---------------- phase 1a: per-block bucket histogram ----------------
__global__ __launch_bounds__(256) void bucket_hist(const int* __restrict__ dst, int E,
                                                   int B1, int chunk, int B0,
                                                   int* __restrict__ H) {
    __shared__ int hist[MAXB1];
    const int blk = blockIdx.x, t = threadIdx.x;
    for (int i = t; i < B1; i += 256) hist[i] = 0;
    __syncthreads();
    const int beg = blk * chunk, end = min(E, beg + chunk);
    for (int e = beg + t; e < end; e += 256) atomicAdd(&hist[dst[e] >> 7], 1);
    __syncthreads();
    for (int i = t; i < B1; i += 256) H[i * B0 + blk] = hist[i];  // bin-major
}

// ---------------- scan A: per-block sums over spans of 2048 ----------------
__global__ __launch_bounds__(256) void scanA(const int* __restrict__ a, int S,
                                             int* __restrict__ bs) {
    __shared__ int s[256];
    const int blk = blockIdx.x, t = threadIdx.x;
    const int base = blk * 2048 + t * 8;
    int sum = 0;
    #pragma unroll
    for (int j = 0; j < 8; ++j) { int idx = base + j; if (idx < S) sum += a[idx]; }
    s[t] = sum;
    __syncthreads();
    for (int off = 128; off > 0; off >>= 1) {
        if (t < off) s[t] += s[t + off];
        __syncthreads();
    }
    if (t == 0) bs[blk] = s[0];
}

// ---------------- scan B: exclusive scan of block sums (nB <= 512) ----------
__global__ __launch_bounds__(512) void scanB(int* __restrict__ bs, int nB) {
    __shared__ int s[512];
    const int t = threadIdx.x;
    int v = (t < nB) ? bs[t] : 0;
    s[t] = v;
    __syncthreads();
    for (int off = 1; off < 512; off <<= 1) {
        int x = s[t];
        int y = (t >= off) ? s[t - off] : 0;
        __syncthreads();
        s[t] = x + y;
        __syncthreads();
    }
    if (t < nB) bs[t] = s[t] - v;
}

// ---------------- scan C: in-place exclusive scan (span 2048/block) ---------
__global__ __launch_bounds__(256) void scanC(int* __restrict__ a, int S,
                                             const int* __restrict__ bs) {
    __shared__ int s[256];
    const int blk = blockIdx.x, t = threadIdx.x;
    const int base = blk * 2048 + t * 8;
    int v[8];
    int sum = 0;
    #pragma unroll
    for (int j = 0; j < 8; ++j) { int idx = base + j; v[j] = (idx < S) ? a[idx] : 0; sum += v[j]; }
    s[t] = sum;
    __syncthreads();
    const int own = sum;
    for (int off = 1; off < 256; off <<= 1) {
        int x = s[t];
        int y = (t >= off) ? s[t - off] : 0;
        __syncthreads();
        s[t] = x + y;
        __syncthreads();
    }
    int run = bs[blk] + s[t] - own;   // exclusive prefix for this thread's segment
    #pragma unroll
    for (int j = 0; j < 8; ++j) { int idx = base + j; if (idx < S) a[idx] = run; run += v[j]; }
}

// ------- phase 1b: scatter edges into bucket-grouped packed (dlow7,src) -----
__global__ __launch_bounds__(256) void bucket_scatter(const int* __restrict__ src,
                                                      const int* __restrict__ dst,
                                                      int E, int B1, int chunk, int B0,
                                                      const int* __restrict__ Hs,
                                                      int* __restrict__ pairs) {
    __shared__ int cur[MAXB1];
    const int blk = blockIdx.x, t = threadIdx.x;
    for (int i = t; i < B1; i += 256) cur[i] = Hs[i * B0 + blk];
    __syncthreads();
    const int beg = blk * chunk, end = min(E, beg + chunk);
    for (int e = beg + t; e < end; e += 256) {
        int d = dst[e];
        int pos = atomicAdd(&cur[d >> 7], 1);          // LDS atomic
        pairs[pos] = ((d & 127) << 17) | src[e];       // src < 2^17
    }
}

// ---------------- phase 2: per-bucket local counting sort -> CSR ------------
__global__ __launch_bounds__(256) void bucket_csr(const int* __restrict__ pairs,
                                                  const int* __restrict__ Hs,
                                                  int B0, int E, int N,
                                                  float* __restrict__ dinv,
                                                  int* __restrict__ rowStart,
                                                  int* __restrict__ srcSorted) {
    __shared__ int hist[NPB], pref[NPB], cur[NPB];
    const int b = blockIdx.x, t = threadIdx.x;
    const int B1 = gridDim.x;
    const int vbase = b * NPB;
    const int nv = min(NPB, N - vbase);
    const int estart = Hs[b * B0];
    const int eend = (b + 1 < B1) ? Hs[(b + 1) * B0] : E;

    if (t < NPB) hist[t] = 0;
    __syncthreads();
    for (int e = estart + t; e < eend; e += 256)
        atomicAdd(&hist[pairs[e] >> 17], 1);
    __syncthreads();

    if (t < NPB) pref[t] = hist[t];
    __syncthreads();
    for (int off = 1; off < NPB; off <<= 1) {
        int v = 0;
        if (t < NPB && t >= off) v = pref[t - off];
        __syncthreads();
        if (t < NPB) pref[t] += v;
        __syncthreads();
    }
    if (t < nv) {
        int ex = pref[t] - hist[t];          // exclusive prefix
        rowStart[vbase + t] = estart + ex;
        dinv[vbase + t] = rsqrtf((float)(hist[t] + 1));
        cur[t] = estart + ex;
    }
    if (b == B1 - 1 && t == 0) rowStart[N] = E;
    __syncthreads();
    for (int e = estart + t; e < eend; e += 256) {
        int p = pairs[e];
        int pos = atomicAdd(&cur[p >> 17], 1);       // LDS atomic
        srcSorted[pos] = p & 0x1FFFF;
    }
}

// ------- GEMM: W in LDS, 4 rows x 8 cols per thread, bf16 output ------------
// Block = 256 threads, 128 rows/block. Thread t: col-group cq=t&7 (cols
// 8cq..8cq+7), row-group rg=t>>3 (rows 4rg..4rg+3 of the tile).
// Per k: 8 W floats (2x ds_read_b128, 8-way broadcast, conflict-free) feed
// 32 FMAs -> 1 B LDS per FMA (r7 was 4 B/FMA -> LDS-bound).
template <int K>
__global__ __launch_bounds__(256, 4) void gemm_scale(const float* __restrict__ X,
                                                     const float* __restrict__ W,
                                                     const float* __restrict__ dinv,
                                                     unsigned short* __restrict__ G, int N) {
    __shared__ float Wl[K * FDIM];
    const int t = threadIdx.x;
    {
        const float4* Wv  = reinterpret_cast<const float4*>(W);
        float4*       Wlv = reinterpret_cast<float4*>(Wl);
        #pragma unroll
        for (int i = 0; i < (K * FDIM) / (256 * 4); ++i)
            Wlv[i * 256 + t] = Wv[i * 256 + t];
    }
    __syncthreads();

    const int cq = t & 7;                    // col-group: cols 8cq..8cq+7
    const int rg = t >> 3;                   // row-group: 4 rows
    const int r0 = blockIdx.x * 128 + rg * 4;
    if (r0 >= N) return;                     // no barriers below

    // clamped row indices for loads (results of clamped rows discarded)
    const int rA = r0;
    const int rB = min(r0 + 1, N - 1);
    const int rC = min(r0 + 2, N - 1);
    const int rD = min(r0 + 3, N - 1);
    const float4* xrA = reinterpret_cast<const float4*>(X + (size_t)rA * K);
    const float4* xrB = reinterpret_cast<const float4*>(X + (size_t)rB * K);
    const float4* xrC = reinterpret_cast<const float4*>(X + (size_t)rC * K);
    const float4* xrD = reinterpret_cast<const float4*>(X + (size_t)rD * K);

    float acc[4][8];
    #pragma unroll
    for (int i = 0; i < 4; ++i)
        #pragma unroll
        for (int c = 0; c < 8; ++c) acc[i][c] = 0.f;

    #pragma unroll 2
    for (int k4 = 0; k4 < K / 4; ++k4) {
        float4 xv0 = xrA[k4], xv1 = xrB[k4], xv2 = xrC[k4], xv3 = xrD[k4];
        float xs0[4] = {xv0.x, xv0.y, xv0.z, xv0.w};
        float xs1[4] = {xv1.x, xv1.y, xv1.z, xv1.w};
        float xs2[4] = {xv2.x, xv2.y, xv2.z, xv2.w};
        float xs3[4] = {xv3.x, xv3.y, xv3.z, xv3.w};
        #pragma unroll
        for (int j = 0; j < 4; ++j) {
            const float4* wp = reinterpret_cast<const float4*>(Wl + (size_t)(4 * k4 + j) * FDIM + cq * 8);
            float4 w0 = wp[0], w1 = wp[1];
            float wv[8] = {w0.x, w0.y, w0.z, w0.w, w1.x, w1.y, w1.z, w1.w};
            #pragma unroll
            for (int c = 0; c < 8; ++c) {
                acc[0][c] += xs0[j] * wv[c];
                acc[1][c] += xs1[j] * wv[c];
                acc[2][c] += xs2[j] * wv[c];
                acc[3][c] += xs3[j] * wv[c];
            }
        }
    }

    #pragma unroll
    for (int i = 0; i < 4; ++i) {
        const int r = r0 + i;
        if (r < N) {
            const float dv = dinv[r];
            unsigned int p0 = f2bf(acc[i][0] * dv) | (f2bf(acc[i][1] * dv) << 16);
            unsigned int p1 = f2bf(acc[i][2] * dv) | (f2bf(acc[i][3] * dv) << 16);
            unsigned int p2 = f2bf(acc[i][4] * dv) | (f2bf(acc[i][5] * dv) << 16);
            unsigned int p3 = f2bf(acc[i][6] * dv) | (f2bf(acc[i][7] * dv) << 16);
            *reinterpret_cast<uint4*>(G + (size_t)r * FDIM + cq * 8) = make_uint4(p0, p1, p2, p3);
        }
    }
}

// ------- aggregate: wave/node, half-wave pair-gather, named-scalar pipeline --
#define GATHER2(ii, uu, off)  int ii = srcSorted[eb + 2*(off)]; \
                              unsigned int uu = Gu[(size_t)ii * 32 + fl];

__global__ __launch_bounds__(256, 4) void aggregate(const unsigned int* __restrict__ Gu,
                                                    const int* __restrict__ rowStart,
                                                    const int* __restrict__ srcSorted,
                                                    const float* __restrict__ dinv,
                                                    const float* __restrict__ bias,
                                                    float* __restrict__ OUT, int N, int doRelu) {
    const int lane   = threadIdx.x & 63;
    const int half   = lane >> 5;        // 0: even edges, 1: odd edges
    const int fl     = lane & 31;        // uint index within row (features 2fl,2fl+1)
    const int waveId = blockIdx.x * (blockDim.x >> 6) + (threadIdx.x >> 6);
    const int nWaves = gridDim.x * (blockDim.x >> 6);
    const float2 bv  = reinterpret_cast<const float2*>(bias)[fl];

    for (int v = waveId; v < N; v += nWaves) {
        const int beg = rowStart[v];
        const int end = rowStart[v + 1];

        unsigned int su = 0;
        if (half == 0) su = Gu[(size_t)v * 32 + fl];
        float ax = lof(su), ay = hif(su);

        int e = beg;
        for (; e + 16 <= end; e += 16) {
            const int eb = e + half;
            GATHER2(i0, u0, 0) GATHER2(i1, u1, 1) GATHER2(i2, u2, 2) GATHER2(i3, u3, 3)
            GATHER2(i4, u4, 4) GATHER2(i5, u5, 5) GATHER2(i6, u6, 6) GATHER2(i7, u7, 7)
            ax += ((lof(u0) + lof(u1)) + (lof(u2) + lof(u3)))
                + ((lof(u4) + lof(u5)) + (lof(u6) + lof(u7)));
            ay += ((hif(u0) + hif(u1)) + (hif(u2) + hif(u3)))
                + ((hif(u4) + hif(u5)) + (hif(u6) + hif(u7)));
        }
        int rem = end - e;
        if (rem >= 8) {
            const int eb = e + half;
            GATHER2(i0, u0, 0) GATHER2(i1, u1, 1) GATHER2(i2, u2, 2) GATHER2(i3, u3, 3)
            ax += (lof(u0) + lof(u1)) + (lof(u2) + lof(u3));
            ay += (hif(u0) + hif(u1)) + (hif(u2) + hif(u3));
            e += 8; rem -= 8;
        }
        if (rem >= 4) {
            const int eb = e + half;
            GATHER2(i0, u0, 0) GATHER2(i1, u1, 1)
            ax += lof(u0) + lof(u1);
            ay += hif(u0) + hif(u1);
            e += 4; rem -= 4;
        }
        if (rem >= 2) {
            const int eb = e + half;
            GATHER2(i0, u0, 0)
            ax += lof(u0);
            ay += hif(u0);
            e += 2; rem -= 2;
        }
        if (rem) {
            int i0 = srcSorted[e];
            unsigned int u0 = 0;
            if (half == 0) u0 = Gu[(size_t)i0 * 32 + fl];
            ax += lof(u0);
            ay += hif(u0);
        }

        ax += __shfl_xor(ax, 32, 64);
        ay += __shfl_xor(ay, 32, 64);

        const float dv = dinv[v];
        float2 r;
        r.x = ax * dv + bv.x;
        r.y = ay * dv + bv.y;
        if (doRelu) { r.x = fmaxf(r.x, 0.f); r.y = fmaxf(r.y, 0.f); }
        if (half == 0)
            reinterpret_cast<float2*>(OUT + (size_t)v * FDIM)[fl] = r;
    }
}

extern "C" void kernel_launch(void* const* d_in, const int* in_sizes, int n_in,
                              void* d_out, int out_size, void* d_ws, size_t ws_size,
                              hipStream_t stream) {
    const float* x     = (const float*)d_in[0];
    const int*   edges = (const int*)d_in[1];   // int32 per harness contract
    const float* W1    = (const float*)d_in[2];
    const float* b1    = (const float*)d_in[3];
    const float* W2    = (const float*)d_in[4];
    const float* b2    = (const float*)d_in[5];
    float*       out   = (float*)d_out;

    const int N = in_sizes[0] / 128;   // 100000
    const int E = in_sizes[1] / 2;     // 1600000
    const int* srcIdx = edges;
    const int* dstIdx = edges + E;

    const int B1 = (N + NPB - 1) / NPB;         // 782 buckets
    const int B0 = 256;                          // phase-1 blocks
    const int chunk = (E + B0 - 1) / B0;         // 6250
    const int S  = B1 * B0;                      // scanned size (200192)
    const int nSB = (S + 2047) / 2048;           // 98 scan blocks (<=512)

    // workspace layout (256B aligned slices)
    char* ws = (char*)d_ws;
    size_t off = 0;
    auto alloc = [&](size_t bytes) { char* p = ws + off; off = (off + bytes + 255) & ~(size_t)255; return p; };
    float* dinv      = (float*)alloc((size_t)N * 4);
    int*   H         = (int*)  alloc((size_t)S * 4);
    int*   blockSums = (int*)  alloc(512 * 4);
    int*   rowStart  = (int*)  alloc((size_t)(N + 1) * 4);
    int*   srcSorted = (int*)  alloc((size_t)E * 4);
    unsigned short* g1 = (unsigned short*)alloc((size_t)N * FDIM * 2);  // bf16
    float* x2        = (float*)alloc((size_t)N * FDIM * 4);
    int*   pairs     = (int*)x2;        // alias: pairs dead before x2 written
    unsigned short* g2 = g1;            // g1 dead after first aggregate

    const int gT = (N + 127) / 128;   // 782 GEMM tiles (128 rows each)

    bucket_hist   <<<B0, 256, 0, stream>>>(dstIdx, E, B1, chunk, B0, H);
    scanA         <<<nSB, 256, 0, stream>>>(H, S, blockSums);
    scanB         <<<1, 512, 0, stream>>>(blockSums, nSB);
    scanC         <<<nSB, 256, 0, stream>>>(H, S, blockSums);
    bucket_scatter<<<B0, 256, 0, stream>>>(srcIdx, dstIdx, E, B1, chunk, B0, H, pairs);
    bucket_csr    <<<B1, 256, 0, stream>>>(pairs, H, B0, E, N, dinv, rowStart, srcSorted);

    gemm_scale<128><<<gT, 256, 0, stream>>>(x,  W1, dinv, g1, N);
    aggregate      <<<2048, 256, 0, stream>>>((const unsigned int*)g1, rowStart, srcSorted, dinv, b1, x2, N, 1);
    gemm_scale<64> <<<gT, 256, 0, stream>>>(x2, W2, dinv, g2, N);
    aggregate      <<<2048, 256, 0, stream>>>((const unsigned int*)g2, rowStart, srcSorted, dinv, b2, out, N, 0);
}

// Round 9
// 187.446 us; speedup vs baseline: 1.7484x; 1.0242x over previous
//
#include <hip/hip_runtime.h>
#include <hip/hip_bf16.h>

// 2-layer GCN on MI355X.
// out[v] = dinv[v] * ( sum_{e: dst=v} g[src_e] + g[v] ) + b,  g = (x@W) * dinv[row]
// dinv[v] = rsqrt(indeg(v) + 1)
// CSR build = bucketed counting sort, ALL atomics in LDS (no device atomics).
// g1/g2 stored BF16. aggregate: half-wave pair-gather, named-scalar pipeline.
// GEMM: W in LDS, 4 rows x 8 cols per thread, EXPLICIT 1-deep X prefetch
// (r8 lesson: compiler doesn't pipeline the X loads -> latency-bound, VALU 34%).

#define FDIM 64    // HID_DIM == OUT_DIM
#define NPB  128   // nodes per bucket (dst >> 7)
#define MAXB1 800  // >= ceil(100000/128)=782

// bf16 helpers (bit-level; finite data only)
static __device__ __forceinline__ unsigned short f2bf(float f) {
    unsigned int u = __float_as_uint(f);
    unsigned int r = 0x7FFFu + ((u >> 16) & 1u);
    return (unsigned short)((u + r) >> 16);
}
static __device__ __forceinline__ float lof(unsigned int u) {   // low bf16 -> f32
    return __uint_as_float(u << 16);
}
static __device__ __forceinline__ float hif(unsigned int u) {   // high bf16 -> f32
    return __uint_as_float(u & 0xFFFF0000u);
}

// ---------------- phase 1a: per-block bucket histogram ----------------
__global__ __launch_bounds__(256) void bucket_hist(const int* __restrict__ dst, int E,
                                                   int B1, int chunk, int B0,
                                                   int* __restrict__ H) {
    __shared__ int hist[MAXB1];
    const int blk = blockIdx.x, t = threadIdx.x;
    for (int i = t; i < B1; i += 256) hist[i] = 0;
    __syncthreads();
    const int beg = blk * chunk, end = min(E, beg + chunk);
    for (int e = beg + t; e < end; e += 256) atomicAdd(&hist[dst[e] >> 7], 1);
    __syncthreads();
    for (int i = t; i < B1; i += 256) H[i * B0 + blk] = hist[i];  // bin-major
}

// ---------------- scan A: per-block sums over spans of 2048 ----------------
__global__ __launch_bounds__(256) void scanA(const int* __restrict__ a, int S,
                                             int* __restrict__ bs) {
    __shared__ int s[256];
    const int blk = blockIdx.x, t = threadIdx.x;
    const int base = blk * 2048 + t * 8;
    int sum = 0;
    #pragma unroll
    for (int j = 0; j < 8; ++j) { int idx = base + j; if (idx < S) sum += a[idx]; }
    s[t] = sum;
    __syncthreads();
    for (int off = 128; off > 0; off >>= 1) {
        if (t < off) s[t] += s[t + off];
        __syncthreads();
    }
    if (t == 0) bs[blk] = s[0];
}

// ---------------- scan B: exclusive scan of block sums (nB <= 512) ----------
__global__ __launch_bounds__(512) void scanB(int* __restrict__ bs, int nB) {
    __shared__ int s[512];
    const int t = threadIdx.x;
    int v = (t < nB) ? bs[t] : 0;
    s[t] = v;
    __syncthreads();
    for (int off = 1; off < 512; off <<= 1) {
        int x = s[t];
        int y = (t >= off) ? s[t - off] : 0;
        __syncthreads();
        s[t] = x + y;
        __syncthreads();
    }
    if (t < nB) bs[t] = s[t] - v;
}

// ---------------- scan C: in-place exclusive scan (span 2048/block) ---------
__global__ __launch_bounds__(256) void scanC(int* __restrict__ a, int S,
                                             const int* __restrict__ bs) {
    __shared__ int s[256];
    const int blk = blockIdx.x, t = threadIdx.x;
    const int base = blk * 2048 + t * 8;
    int v[8];
    int sum = 0;
    #pragma unroll
    for (int j = 0; j < 8; ++j) { int idx = base + j; v[j] = (idx < S) ? a[idx] : 0; sum += v[j]; }
    s[t] = sum;
    __syncthreads();
    const int own = sum;
    for (int off = 1; off < 256; off <<= 1) {
        int x = s[t];
        int y = (t >= off) ? s[t - off] : 0;
        __syncthreads();
        s[t] = x + y;
        __syncthreads();
    }
    int run = bs[blk] + s[t] - own;   // exclusive prefix for this thread's segment
    #pragma unroll
    for (int j = 0; j < 8; ++j) { int idx = base + j; if (idx < S) a[idx] = run; run += v[j]; }
}

// ------- phase 1b: scatter edges into bucket-grouped packed (dlow7,src) -----
__global__ __launch_bounds__(256) void bucket_scatter(const int* __restrict__ src,
                                                      const int* __restrict__ dst,
                                                      int E, int B1, int chunk, int B0,
                                                      const int* __restrict__ Hs,
                                                      int* __restrict__ pairs) {
    __shared__ int cur[MAXB1];
    const int blk = blockIdx.x, t = threadIdx.x;
    for (int i = t; i < B1; i += 256) cur[i] = Hs[i * B0 + blk];
    __syncthreads();
    const int beg = blk * chunk, end = min(E, beg + chunk);
    for (int e = beg + t; e < end; e += 256) {
        int d = dst[e];
        int pos = atomicAdd(&cur[d >> 7], 1);          // LDS atomic
        pairs[pos] = ((d & 127) << 17) | src[e];       // src < 2^17
    }
}

// ---------------- phase 2: per-bucket local counting sort -> CSR ------------
__global__ __launch_bounds__(256) void bucket_csr(const int* __restrict__ pairs,
                                                  const int* __restrict__ Hs,
                                                  int B0, int E, int N,
                                                  float* __restrict__ dinv,
                                                  int* __restrict__ rowStart,
                                                  int* __restrict__ srcSorted) {
    __shared__ int hist[NPB], pref[NPB], cur[NPB];
    const int b = blockIdx.x, t = threadIdx.x;
    const int B1 = gridDim.x;
    const int vbase = b * NPB;
    const int nv = min(NPB, N - vbase);
    const int estart = Hs[b * B0];
    const int eend = (b + 1 < B1) ? Hs[(b + 1) * B0] : E;

    if (t < NPB) hist[t] = 0;
    __syncthreads();
    for (int e = estart + t; e < eend; e += 256)
        atomicAdd(&hist[pairs[e] >> 17], 1);
    __syncthreads();

    if (t < NPB) pref[t] = hist[t];
    __syncthreads();
    for (int off = 1; off < NPB; off <<= 1) {
        int v = 0;
        if (t < NPB && t >= off) v = pref[t - off];
        __syncthreads();
        if (t < NPB) pref[t] += v;
        __syncthreads();
    }
    if (t < nv) {
        int ex = pref[t] - hist[t];          // exclusive prefix
        rowStart[vbase + t] = estart + ex;
        dinv[vbase + t] = rsqrtf((float)(hist[t] + 1));
        cur[t] = estart + ex;
    }
    if (b == B1 - 1 && t == 0) rowStart[N] = E;
    __syncthreads();
    for (int e = estart + t; e < eend; e += 256) {
        int p = pairs[e];
        int pos = atomicAdd(&cur[p >> 17], 1);       // LDS atomic
        srcSorted[pos] = p & 0x1FFFF;
    }
}

// ------- GEMM: W in LDS, 4 rows x 8 cols per thread, 1-deep X prefetch ------
// Block = 256 threads, 128 rows/block. Thread t: cq=t&7 (cols 8cq..8cq+7),
// rg=t>>3 (rows 4rg..4rg+3). Per k: 8 W floats (2x ds_read_b128, 8-way
// broadcast, conflict-free) feed 32 FMAs. Next k4's X float4s are loaded
// into NAMED registers before the current FMAs (hides ~400cy L2 latency
// under 256 FMA issue-cycles x 3 waves/SIMD).
template <int K>
__global__ __launch_bounds__(256, 4) void gemm_scale(const float* __restrict__ X,
                                                     const float* __restrict__ W,
                                                     const float* __restrict__ dinv,
                                                     unsigned short* __restrict__ G, int N) {
    __shared__ float Wl[K * FDIM];
    const int t = threadIdx.x;
    {
        const float4* Wv  = reinterpret_cast<const float4*>(W);
        float4*       Wlv = reinterpret_cast<float4*>(Wl);
        #pragma unroll
        for (int i = 0; i < (K * FDIM) / (256 * 4); ++i)
            Wlv[i * 256 + t] = Wv[i * 256 + t];
    }
    __syncthreads();

    const int cq = t & 7;                    // col-group: cols 8cq..8cq+7
    const int rg = t >> 3;                   // row-group: 4 rows
    const int r0 = blockIdx.x * 128 + rg * 4;
    if (r0 >= N) return;                     // no barriers below

    const int rA = r0;
    const int rB = min(r0 + 1, N - 1);
    const int rC = min(r0 + 2, N - 1);
    const int rD = min(r0 + 3, N - 1);
    const float4* xrA = reinterpret_cast<const float4*>(X + (size_t)rA * K);
    const float4* xrB = reinterpret_cast<const float4*>(X + (size_t)rB * K);
    const float4* xrC = reinterpret_cast<const float4*>(X + (size_t)rC * K);
    const float4* xrD = reinterpret_cast<const float4*>(X + (size_t)rD * K);

    float acc[4][8];
    #pragma unroll
    for (int i = 0; i < 4; ++i)
        #pragma unroll
        for (int c = 0; c < 8; ++c) acc[i][c] = 0.f;

    // one k4 step: 4 k-values, 8 W floats each, 128 FMAs
    auto do_k4 = [&](int k4, float4 c0, float4 c1, float4 c2, float4 c3) {
        float xs0[4] = {c0.x, c0.y, c0.z, c0.w};
        float xs1[4] = {c1.x, c1.y, c1.z, c1.w};
        float xs2[4] = {c2.x, c2.y, c2.z, c2.w};
        float xs3[4] = {c3.x, c3.y, c3.z, c3.w};
        #pragma unroll
        for (int j = 0; j < 4; ++j) {
            const float4* wp = reinterpret_cast<const float4*>(Wl + (size_t)(4 * k4 + j) * FDIM + cq * 8);
            float4 w0 = wp[0], w1 = wp[1];
            float wv[8] = {w0.x, w0.y, w0.z, w0.w, w1.x, w1.y, w1.z, w1.w};
            #pragma unroll
            for (int c = 0; c < 8; ++c) {
                acc[0][c] += xs0[j] * wv[c];
                acc[1][c] += xs1[j] * wv[c];
                acc[2][c] += xs2[j] * wv[c];
                acc[3][c] += xs3[j] * wv[c];
            }
        }
    };

    // 1-deep prefetch pipeline over k4 = 0 .. K/4-1 (last iter peeled)
    float4 nA = xrA[0], nB = xrB[0], nC = xrC[0], nD = xrD[0];
    #pragma unroll 4
    for (int k4 = 0; k4 < K / 4 - 1; ++k4) {
        float4 cA = nA, cB = nB, cC = nC, cD = nD;
        nA = xrA[k4 + 1]; nB = xrB[k4 + 1]; nC = xrC[k4 + 1]; nD = xrD[k4 + 1];
        do_k4(k4, cA, cB, cC, cD);
    }
    do_k4(K / 4 - 1, nA, nB, nC, nD);

    #pragma unroll
    for (int i = 0; i < 4; ++i) {
        const int r = r0 + i;
        if (r < N) {
            const float dv = dinv[r];
            unsigned int p0 = f2bf(acc[i][0] * dv) | (f2bf(acc[i][1] * dv) << 16);
            unsigned int p1 = f2bf(acc[i][2] * dv) | (f2bf(acc[i][3] * dv) << 16);
            unsigned int p2 = f2bf(acc[i][4] * dv) | (f2bf(acc[i][5] * dv) << 16);
            unsigned int p3 = f2bf(acc[i][6] * dv) | (f2bf(acc[i][7] * dv) << 16);
            *reinterpret_cast<uint4*>(G + (size_t)r * FDIM + cq * 8) = make_uint4(p0, p1, p2, p3);
        }
    }
}

// ------- aggregate: wave/node, half-wave pair-gather, named-scalar pipeline --
#define GATHER2(ii, uu, off)  int ii = srcSorted[eb + 2*(off)]; \
                              unsigned int uu = Gu[(size_t)ii * 32 + fl];

__global__ __launch_bounds__(256, 4) void aggregate(const unsigned int* __restrict__ Gu,
                                                    const int* __restrict__ rowStart,
                                                    const int* __restrict__ srcSorted,
                                                    const float* __restrict__ dinv,
                                                    const float* __restrict__ bias,
                                                    float* __restrict__ OUT, int N, int doRelu) {
    const int lane   = threadIdx.x & 63;
    const int half   = lane >> 5;        // 0: even edges, 1: odd edges
    const int fl     = lane & 31;        // uint index within row (features 2fl,2fl+1)
    const int waveId = blockIdx.x * (blockDim.x >> 6) + (threadIdx.x >> 6);
    const int nWaves = gridDim.x * (blockDim.x >> 6);
    const float2 bv  = reinterpret_cast<const float2*>(bias)[fl];

    for (int v = waveId; v < N; v += nWaves) {
        const int beg = rowStart[v];
        const int end = rowStart[v + 1];

        unsigned int su = 0;
        if (half == 0) su = Gu[(size_t)v * 32 + fl];
        float ax = lof(su), ay = hif(su);

        int e = beg;
        for (; e + 16 <= end; e += 16) {
            const int eb = e + half;
            GATHER2(i0, u0, 0) GATHER2(i1, u1, 1) GATHER2(i2, u2, 2) GATHER2(i3, u3, 3)
            GATHER2(i4, u4, 4) GATHER2(i5, u5, 5) GATHER2(i6, u6, 6) GATHER2(i7, u7, 7)
            ax += ((lof(u0) + lof(u1)) + (lof(u2) + lof(u3)))
                + ((lof(u4) + lof(u5)) + (lof(u6) + lof(u7)));
            ay += ((hif(u0) + hif(u1)) + (hif(u2) + hif(u3)))
                + ((hif(u4) + hif(u5)) + (hif(u6) + hif(u7)));
        }
        int rem = end - e;
        if (rem >= 8) {
            const int eb = e + half;
            GATHER2(i0, u0, 0) GATHER2(i1, u1, 1) GATHER2(i2, u2, 2) GATHER2(i3, u3, 3)
            ax += (lof(u0) + lof(u1)) + (lof(u2) + lof(u3));
            ay += (hif(u0) + hif(u1)) + (hif(u2) + hif(u3));
            e += 8; rem -= 8;
        }
        if (rem >= 4) {
            const int eb = e + half;
            GATHER2(i0, u0, 0) GATHER2(i1, u1, 1)
            ax += lof(u0) + lof(u1);
            ay += hif(u0) + hif(u1);
            e += 4; rem -= 4;
        }
        if (rem >= 2) {
            const int eb = e + half;
            GATHER2(i0, u0, 0)
            ax += lof(u0);
            ay += hif(u0);
            e += 2; rem -= 2;
        }
        if (rem) {
            int i0 = srcSorted[e];
            unsigned int u0 = 0;
            if (half == 0) u0 = Gu[(size_t)i0 * 32 + fl];
            ax += lof(u0);
            ay += hif(u0);
        }

        ax += __shfl_xor(ax, 32, 64);
        ay += __shfl_xor(ay, 32, 64);

        const float dv = dinv[v];
        float2 r;
        r.x = ax * dv + bv.x;
        r.y = ay * dv + bv.y;
        if (doRelu) { r.x = fmaxf(r.x, 0.f); r.y = fmaxf(r.y, 0.f); }
        if (half == 0)
            reinterpret_cast<float2*>(OUT + (size_t)v * FDIM)[fl] = r;
    }
}

extern "C" void kernel_launch(void* const* d_in, const int* in_sizes, int n_in,
                              void* d_out, int out_size, void* d_ws, size_t ws_size,
                              hipStream_t stream) {
    const float* x     = (const float*)d_in[0];
    const int*   edges = (const int*)d_in[1];   // int32 per harness contract
    const float* W1    = (const float*)d_in[2];
    const float* b1    = (const float*)d_in[3];
    const float* W2    = (const float*)d_in[4];
    const float* b2    = (const float*)d_in[5];
    float*       out   = (float*)d_out;

    const int N = in_sizes[0] / 128;   // 100000
    const int E = in_sizes[1] / 2;     // 1600000
    const int* srcIdx = edges;
    const int* dstIdx = edges + E;

    const int B1 = (N + NPB - 1) / NPB;         // 782 buckets
    const int B0 = 256;                          // phase-1 blocks
    const int chunk = (E + B0 - 1) / B0;         // 6250
    const int S  = B1 * B0;                      // scanned size (200192)
    const int nSB = (S + 2047) / 2048;           // 98 scan blocks (<=512)

    // workspace layout (256B aligned slices)
    char* ws = (char*)d_ws;
    size_t off = 0;
    auto alloc = [&](size_t bytes) { char* p = ws + off; off = (off + bytes + 255) & ~(size_t)255; return p; };
    float* dinv      = (float*)alloc((size_t)N * 4);
    int*   H         = (int*)  alloc((size_t)S * 4);
    int*   blockSums = (int*)  alloc(512 * 4);
    int*   rowStart  = (int*)  alloc((size_t)(N + 1) * 4);
    int*   srcSorted = (int*)  alloc((size_t)E * 4);
    unsigned short* g1 = (unsigned short*)alloc((size_t)N * FDIM * 2);  // bf16
    float* x2        = (float*)alloc((size_t)N * FDIM * 4);
    int*   pairs     = (int*)x2;        // alias: pairs dead before x2 written
    unsigned short* g2 = g1;            // g1 dead after first aggregate

    const int gT = (N + 127) / 128;   // 782 GEMM tiles (128 rows each)

    bucket_hist   <<<B0, 256, 0, stream>>>(dstIdx, E, B1, chunk, B0, H);
    scanA         <<<nSB, 256, 0, stream>>>(H, S, blockSums);
    scanB         <<<1, 512, 0, stream>>>(blockSums, nSB);
    scanC         <<<nSB, 256, 0, stream>>>(H, S, blockSums);
    bucket_scatter<<<B0, 256, 0, stream>>>(srcIdx, dstIdx, E, B1, chunk, B0, H, pairs);
    bucket_csr    <<<B1, 256, 0, stream>>>(pairs, H, B0, E, N, dinv, rowStart, srcSorted);

    gemm_scale<128><<<gT, 256, 0, stream>>>(x,  W1, dinv, g1, N);
    aggregate      <<<2048, 256, 0, stream>>>((const unsigned int*)g1, rowStart, srcSorted, dinv, b1, x2, N, 1);
    gemm_scale<64> <<<gT, 256, 0, stream>>>(x2, W2, dinv, g2, N);
    aggregate      <<<2048, 256, 0, stream>>>((const unsigned int*)g2, rowStart, srcSorted, dinv, b2, out, N, 0);
}